// Round 12
// baseline (370.097 us; speedup 1.0000x reference)
//
#include <hip/hip_runtime.h>

// LinOSS: damped-oscillator linear SSM scan. B=8, T=2048, H=16, D=64.
//   sigma = sigmoid(osc_damp); a = DT*exp(osc_w)   (per h,d,e element)
//   z' = (1-sigma)*z - a*y + DT*beta*k[d]*v[e]
//   y' = y + DT*z'
//   out[b,t,h,e] = (1/8) * sum_d q[b,t,h,d] * y[d,e]
//
// Two-pass chunk-parallel over T; R11 analysis: DS-pipe bound (predicted
// VALU cap 69% == measured 71%). R12: 16 elems/thread (8d x 2e), block
// covers full 64x64 (b,h) tile -> per-element DS cost halves (same k/q
// b128 reads serve 2 e-columns), vv = one b64, out = one dwordx2.

constexpr float DTc = 0.01f;
constexpr int Tn = 2048, Hn = 16, Dn = 64;
constexpr int TS = Hn * Dn; // 1024 floats per t-step in q/k/v/out
constexpr int TILE = 16;

typedef const __attribute__((address_space(1))) void* as1_cvp;
typedef __attribute__((address_space(3))) void* as3_vp;

__device__ __forceinline__ void gload_lds4(const float* g, float* lds) {
    __builtin_amdgcn_global_load_lds((as1_cvp)g, (as3_vp)lds, 4, 0, 0);
}
__device__ __forceinline__ void gload_lds16(const float* g, float* lds) {
    __builtin_amdgcn_global_load_lds((as1_cvp)g, (as3_vp)lds, 16, 0, 0);
}

// In-quad butterfly add on the VALU pipe (quad_perm DPP, exact semantics).
template<int CTRL>
__device__ __forceinline__ float dpp_add(float x) {
    int yi = __builtin_amdgcn_update_dpp(0, __float_as_int(x), CTRL, 0xF, 0xF, true);
    return x + __int_as_float(yi);
}

// TAIL: chunks 0..NC-2, no q/out, store final state to ws.
// !TAIL: chunks 0..NC-1, reconstruct start state from ws, write out.
template<int NC, bool TAIL>
__global__ __launch_bounds__(256, 4)
void linoss_k(const float* __restrict__ Q, const float* __restrict__ K,
              const float* __restrict__ V, const float* __restrict__ Bt,
              const float* __restrict__ OW, const float* __restrict__ OD,
              float* __restrict__ Out, float* __restrict__ WS) {
    constexpr int L = Tn / NC;
    constexpr bool WQ = !TAIL;

    __shared__ float sK[2][TILE][64];
    __shared__ float sQ[WQ ? 2 : 1][WQ ? TILE : 1][WQ ? 64 : 1];
    __shared__ float sV[2][TILE][64];
    __shared__ float sB[2][TILE];

    int blk = blockIdx.x;
    int c = blk >> 7;       // chunk index (grid = NC*128)
    int bh = blk & 127;
    int b = bh >> 4, h = bh & 15;

    int tid = threadIdx.x;
    int dgrp = tid & 7;     // 8 d-groups
    int ep = tid >> 3;      // 0..31 e-pair index
    int d0 = dgrp * 8;
    int e0 = ep * 2;        // two e-columns per thread
    int wv = tid >> 6;      // wave id 0..3
    int ln = tid & 63;      // lane

    float aDT[2][8], omc[2][8];
#pragma unroll
    for (int col = 0; col < 2; ++col)
#pragma unroll
        for (int j = 0; j < 8; ++j) {
            int idx = (h * Dn + d0 + j) * Dn + (e0 + col);
            aDT[col][j] = DTc * expf(OW[idx]);
            omc[col][j] = 1.0f - 1.0f / (1.0f + expf(-OD[idx]));
        }

    float y[2][8], z[2][8];
#pragma unroll
    for (int col = 0; col < 2; ++col)
#pragma unroll
        for (int j = 0; j < 8; ++j) { y[col][j] = 0.0f; z[col][j] = 0.0f; }

    // per-(c,bh) ws tile: 256 threads x 16 elems x {y,z} = 8192 floats
    auto wsBase = [&](int ci) {
        return WS + ((size_t)ci * 128 + bh) * 8192 + (size_t)tid * 32;
    };

    if (!TAIL && c > 0) {
        // per e-column to bound register pressure
#pragma unroll
        for (int col = 0; col < 2; ++col) {
            float m00[8], m01[8], m10[8], m11[8];
#pragma unroll
            for (int j = 0; j < 8; ++j) {
                m00[j] = 1.0f - DTc * aDT[col][j];
                m01[j] = DTc * omc[col][j];
                m10[j] = -aDT[col][j];
                m11[j] = omc[col][j];
            }
            for (int pw = 1; pw < L; pw <<= 1) {
#pragma unroll
                for (int j = 0; j < 8; ++j) {
                    float n00 = fmaf(m00[j], m00[j], m01[j] * m10[j]);
                    float n01 = fmaf(m00[j], m01[j], m01[j] * m11[j]);
                    float n10 = fmaf(m10[j], m00[j], m11[j] * m10[j]);
                    float n11 = fmaf(m10[j], m01[j], m11[j] * m11[j]);
                    m00[j] = n00; m01[j] = n01; m10[j] = n10; m11[j] = n11;
                }
            }
            for (int i = 0; i < c; ++i) {
                const float4* cw = (const float4*)wsBase(i) + col * 4;
                float4 w0 = cw[0], w1 = cw[1], w2 = cw[2], w3 = cw[3];
                float cy[8] = {w0.x, w0.z, w1.x, w1.z, w2.x, w2.z, w3.x, w3.z};
                float cz[8] = {w0.y, w0.w, w1.y, w1.w, w2.y, w2.w, w3.y, w3.w};
#pragma unroll
                for (int j = 0; j < 8; ++j) {
                    float ny = fmaf(m00[j], y[col][j], fmaf(m01[j], z[col][j], cy[j]));
                    float nz = fmaf(m10[j], y[col][j], fmaf(m11[j], z[col][j], cz[j]));
                    y[col][j] = ny; z[col][j] = nz;
                }
            }
        }
    }

    // full-row bases
    size_t bhOff = (size_t)b * Tn * TS + (size_t)h * Dn;
    const float* kb0 = K + bhOff;
    const float* qb0 = Q + bhOff;
    const float* vb0 = V + bhOff;
    const float* bb0 = Bt + (size_t)b * Tn * Hn + h;
    float* op = Out + bhOff + e0;
    bool wlane = (dgrp == 0);

    int t0 = c * L;

    // stage one TILE (16 steps) into LDS via width-16 DMA.
    // K/Q/V rows: 64 floats = 256B -> 16 lanes/row, 4 rows/inst, 1 inst/wave.
    auto stage = [&](int buf, int tt0) {
        {
            int row = 4 * wv + (ln >> 4);
            gload_lds16(kb0 + (size_t)(tt0 + row) * TS + (ln & 15) * 4, &sK[buf][4 * wv][0]);
        }
        if (WQ) {
            int row = 4 * wv + (ln >> 4);
            gload_lds16(qb0 + (size_t)(tt0 + row) * TS + (ln & 15) * 4, &sQ[buf][4 * wv][0]);
        }
        {
            int row = 4 * wv + (ln >> 4);
            gload_lds16(vb0 + (size_t)(tt0 + row) * TS + (ln & 15) * 4, &sV[buf][4 * wv][0]);
        }
        if (wv == 3 && ln < 16)
            gload_lds4(bb0 + (size_t)(tt0 + ln) * Hn, &sB[buf][0]);
    };

    constexpr int nT = L / TILE;
    stage(0, t0);
    __syncthreads();

    for (int ti = 0; ti < nT; ++ti) {
        int cur = ti & 1;
        if (ti + 1 < nT) stage(cur ^ 1, t0 + (ti + 1) * TILE);
        float* ops = op + (size_t)(t0 + ti * TILE) * TS;
#pragma unroll 4
        for (int s = 0; s < TILE; ++s) {
            const float4* kr = (const float4*)&sK[cur][s][d0];
            float4 ka = kr[0], kb = kr[1];
            float2 vv = *(const float2*)&sV[cur][s][e0];
            float bb = sB[cur][s];
            float dtb = DTc * bb;
            float bv0 = dtb * vv.x;
            float bv1 = dtb * vv.y;
            float kk[8] = {ka.x, ka.y, ka.z, ka.w, kb.x, kb.y, kb.z, kb.w};
#pragma unroll
            for (int j = 0; j < 8; ++j) {
                z[0][j] = fmaf(omc[0][j], z[0][j], fmaf(-aDT[0][j], y[0][j], bv0 * kk[j]));
                y[0][j] = fmaf(DTc, z[0][j], y[0][j]);
                z[1][j] = fmaf(omc[1][j], z[1][j], fmaf(-aDT[1][j], y[1][j], bv1 * kk[j]));
                y[1][j] = fmaf(DTc, z[1][j], y[1][j]);
            }
            if (WQ) {
                const float4* qr = (const float4*)&sQ[cur][s][d0];
                float4 qa = qr[0], qb = qr[1];
                float qq[8] = {qa.x, qa.y, qa.z, qa.w, qb.x, qb.y, qb.z, qb.w};
                float p0 = 0.0f, p1 = 0.0f;
#pragma unroll
                for (int j = 0; j < 8; ++j) {
                    p0 = fmaf(qq[j], y[0][j], p0);
                    p1 = fmaf(qq[j], y[1][j], p1);
                }
                p0 = dpp_add<0xB1>(p0);
                p0 = dpp_add<0x4E>(p0);
                p0 += __shfl_xor(p0, 4);
                p1 = dpp_add<0xB1>(p1);
                p1 = dpp_add<0x4E>(p1);
                p1 += __shfl_xor(p1, 4);
                if (wlane) {
                    float2 o = {p0 * 0.125f, p1 * 0.125f}; // scale = D^-0.5
                    *(float2*)ops = o;
                }
                ops += TS;
            }
        }
        __syncthreads();
    }

    if (TAIL) {
        float4* cw = (float4*)wsBase(c);
#pragma unroll
        for (int col = 0; col < 2; ++col)
#pragma unroll
            for (int jj = 0; jj < 4; ++jj) {
                float4 w;
                w.x = y[col][2 * jj];     w.y = z[col][2 * jj];
                w.z = y[col][2 * jj + 1]; w.w = z[col][2 * jj + 1];
                cw[col * 4 + jj] = w;
            }
    }
}

extern "C" void kernel_launch(void* const* d_in, const int* in_sizes, int n_in,
                              void* d_out, int out_size, void* d_ws, size_t ws_size,
                              hipStream_t stream) {
    const float* q  = (const float*)d_in[0];
    const float* k  = (const float*)d_in[1];
    const float* v  = (const float*)d_in[2];
    const float* bt = (const float*)d_in[3];
    const float* ow = (const float*)d_in[4];
    const float* od = (const float*)d_in[5];
    float* out = (float*)d_out;
    float* ws = (float*)d_ws;

    const size_t chunkBytes = (size_t)128 * 8192 * sizeof(float); // 4 MiB

    if (ws_size >= 7 * chunkBytes) {
        // NC=8: main 1024 blocks = exact 4 blocks/CU fill; tail 896.
        hipLaunchKernelGGL((linoss_k<8, true>),  dim3(896),  dim3(256), 0, stream,
                           q, k, v, bt, ow, od, out, ws);
        hipLaunchKernelGGL((linoss_k<8, false>), dim3(1024), dim3(256), 0, stream,
                           q, k, v, bt, ow, od, out, ws);
    } else if (ws_size >= chunkBytes) {
        hipLaunchKernelGGL((linoss_k<2, true>),  dim3(128),  dim3(256), 0, stream,
                           q, k, v, bt, ow, od, out, ws);
        hipLaunchKernelGGL((linoss_k<2, false>), dim3(256),  dim3(256), 0, stream,
                           q, k, v, bt, ow, od, out, ws);
    } else {
        hipLaunchKernelGGL((linoss_k<1, false>), dim3(128),  dim3(256), 0, stream,
                           q, k, v, bt, ow, od, out, ws);
    }
}

// Round 13
// 269.195 us; speedup vs baseline: 1.3748x; 1.3748x over previous
//
#include <hip/hip_runtime.h>

// LinOSS: damped-oscillator linear SSM scan. B=8, T=2048, H=16, D=64.
//   sigma = sigmoid(osc_damp); a = DT*exp(osc_w)   (per h,d,e element)
//   z' = (1-sigma)*z - a*y + DT*beta*k[d]*v[e]
//   y' = y + DT*z'
//   out[b,t,h,e] = (1/8) * sum_d q[b,t,h,d] * y[d,e]
//
// Two-pass chunk-parallel over T. R12 A/B falsified "DS-bound": halved DS,
// VALUBusy stayed 71%, dur rose (TLP loss). Kernel is VALU+short-stall
// bound at the 4-waves/SIMD residency cap. R13 = R11 structure + chunk-0
// merge: L1 runs chunks 0..6 (c=0 blocks do the full q-dot sweep AND store
// ws; c>=1 blocks state-only + ws). L2 runs chunks 1..7. Saves 1/8 of all
// state-update work vs R11's separate tail.

constexpr float DTc = 0.01f;
constexpr int Tn = 2048, Hn = 16, Dn = 64;
constexpr int TS = Hn * Dn; // 1024 floats per t-step in q/k/v/out
constexpr int TILE = 16;

typedef const __attribute__((address_space(1))) void* as1_cvp;
typedef __attribute__((address_space(3))) void* as3_vp;

__device__ __forceinline__ void gload_lds4(const float* g, float* lds) {
    __builtin_amdgcn_global_load_lds((as1_cvp)g, (as3_vp)lds, 4, 0, 0);
}
__device__ __forceinline__ void gload_lds16(const float* g, float* lds) {
    __builtin_amdgcn_global_load_lds((as1_cvp)g, (as3_vp)lds, 16, 0, 0);
}

// In-quad butterfly add on the VALU pipe (quad_perm DPP, exact semantics).
template<int CTRL>
__device__ __forceinline__ float dpp_add(float x) {
    int yi = __builtin_amdgcn_update_dpp(0, __float_as_int(x), CTRL, 0xF, 0xF, true);
    return x + __int_as_float(yi);
}

// MODE 0 (L1): c = blk>>8 in [0, NC-2]; doQ = (c==0); always store ws.
// MODE 1 (L2): c = c0 + (blk>>8); prefix-combine if c>0; q-dot; no ws store.
template<int NC, int MODE>
__global__ __launch_bounds__(256, 4)
void linoss_k(const float* __restrict__ Q, const float* __restrict__ K,
              const float* __restrict__ V, const float* __restrict__ Bt,
              const float* __restrict__ OW, const float* __restrict__ OD,
              float* __restrict__ Out, float* __restrict__ WS, int c0) {
    constexpr int L = Tn / NC;

    __shared__ float sK[2][TILE][64];
    __shared__ float sQ[2][TILE][64];
    __shared__ float sV[2][TILE][32];
    __shared__ float sB[2][TILE];

    int blk = blockIdx.x;
    int c = (MODE == 0) ? (blk >> 8) : (c0 + (blk >> 8));
    bool doQ = (MODE == 1) || (c == 0);
    int sl = blk & 255;
    // XCD-aware decode: both e-halves of the same (b,h) on one XCD.
    int xcd = sl & 7, slot = sl >> 3;
    int ec = slot & 1;
    int bh = ((slot >> 1) << 3) | xcd;
    int b = bh >> 4, h = bh & 15;

    int tid = threadIdx.x;
    int dgrp = tid & 7;
    int el = tid >> 3;
    int e = ec * 32 + el;
    int d0 = dgrp * 8;
    int wv = tid >> 6;      // wave id 0..3
    int ln = tid & 63;      // lane

    float aDT[8], omc[8];
#pragma unroll
    for (int j = 0; j < 8; ++j) {
        int idx = (h * Dn + d0 + j) * Dn + e;
        aDT[j] = DTc * expf(OW[idx]);
        float sg = 1.0f / (1.0f + expf(-OD[idx]));
        omc[j] = 1.0f - sg;
    }

    float y[8], z[8];
#pragma unroll
    for (int j = 0; j < 8; ++j) { y[j] = 0.0f; z[j] = 0.0f; }

    // per-(c,bh,ec) ws tile: 256 threads x 8 elems x {y,z}
    auto wsBase = [&](int ci) {
        return WS + (((size_t)ci * 128 + bh) * 2 + ec) * 4096 + (size_t)tid * 16;
    };

    if (MODE == 1 && c > 0) {
        // A = [[1-DT*a, DT*w],[-a, w]] on (y,z); compute A^L by squaring.
        float m00[8], m01[8], m10[8], m11[8];
#pragma unroll
        for (int j = 0; j < 8; ++j) {
            m00[j] = 1.0f - DTc * aDT[j];
            m01[j] = DTc * omc[j];
            m10[j] = -aDT[j];
            m11[j] = omc[j];
        }
        for (int pw = 1; pw < L; pw <<= 1) {
#pragma unroll
            for (int j = 0; j < 8; ++j) {
                float n00 = fmaf(m00[j], m00[j], m01[j] * m10[j]);
                float n01 = fmaf(m00[j], m01[j], m01[j] * m11[j]);
                float n10 = fmaf(m10[j], m00[j], m11[j] * m10[j]);
                float n11 = fmaf(m10[j], m01[j], m11[j] * m11[j]);
                m00[j] = n00; m01[j] = n01; m10[j] = n10; m11[j] = n11;
            }
        }
        for (int i = 0; i < c; ++i) {
            const float4* cw = (const float4*)wsBase(i);
            float4 w0 = cw[0], w1 = cw[1], w2 = cw[2], w3 = cw[3];
            float cy[8] = {w0.x, w0.z, w1.x, w1.z, w2.x, w2.z, w3.x, w3.z};
            float cz[8] = {w0.y, w0.w, w1.y, w1.w, w2.y, w2.w, w3.y, w3.w};
#pragma unroll
            for (int j = 0; j < 8; ++j) {
                float ny = fmaf(m00[j], y[j], fmaf(m01[j], z[j], cy[j]));
                float nz = fmaf(m10[j], y[j], fmaf(m11[j], z[j], cz[j]));
                y[j] = ny; z[j] = nz;
            }
        }
    }

    // full-row bases
    size_t bhOff = (size_t)b * Tn * TS + (size_t)h * Dn;
    const float* kb0 = K + bhOff;
    const float* qb0 = Q + bhOff;
    const float* vb0 = V + bhOff + ec * 32;
    const float* bb0 = Bt + (size_t)b * Tn * Hn + h;
    float* op = Out + bhOff + e;
    bool wlane = (dgrp == 0);

    int t0 = c * L;

    // stage one TILE (16 steps) into LDS via width-16 DMA (R11-proven map).
    auto stage = [&](int buf, int tt0) {
        {
            int row = 4 * wv + (ln >> 4);
            gload_lds16(kb0 + (size_t)(tt0 + row) * TS + (ln & 15) * 4, &sK[buf][4 * wv][0]);
        }
        if (doQ) {
            int row = 4 * wv + (ln >> 4);
            gload_lds16(qb0 + (size_t)(tt0 + row) * TS + (ln & 15) * 4, &sQ[buf][4 * wv][0]);
        }
        if (wv < 2) {
            int row = 8 * wv + (ln >> 3);
            gload_lds16(vb0 + (size_t)(tt0 + row) * TS + (ln & 7) * 4, &sV[buf][8 * wv][0]);
        }
        if (wv == 2 && ln < 16)
            gload_lds4(bb0 + (size_t)(tt0 + ln) * Hn, &sB[buf][0]);
    };

    constexpr int nT = L / TILE;
    stage(0, t0);
    __syncthreads();

    for (int ti = 0; ti < nT; ++ti) {
        int cur = ti & 1;
        if (ti + 1 < nT) stage(cur ^ 1, t0 + (ti + 1) * TILE);
        float* ops = op + (size_t)(t0 + ti * TILE) * TS;
#pragma unroll 8
        for (int s = 0; s < TILE; ++s) {
            const float4* kr = (const float4*)&sK[cur][s][d0];
            float4 ka = kr[0], kb = kr[1];
            float vv = sV[cur][s][el];
            float bb = sB[cur][s];
            float bv = (DTc * bb) * vv;
            float kk[8] = {ka.x, ka.y, ka.z, ka.w, kb.x, kb.y, kb.z, kb.w};
#pragma unroll
            for (int j = 0; j < 8; ++j) {
                z[j] = fmaf(omc[j], z[j], fmaf(-aDT[j], y[j], bv * kk[j]));
                y[j] = fmaf(DTc, z[j], y[j]);
            }
            if (doQ) {
                const float4* qr = (const float4*)&sQ[cur][s][d0];
                float4 qa = qr[0], qb = qr[1];
                float qq[8] = {qa.x, qa.y, qa.z, qa.w, qb.x, qb.y, qb.z, qb.w};
                float p = 0.0f;
#pragma unroll
                for (int j = 0; j < 8; ++j) p = fmaf(qq[j], y[j], p);
                p = dpp_add<0xB1>(p);   // quad_perm xor1 (exact)
                p = dpp_add<0x4E>(p);   // quad_perm xor2 (exact)
                p += __shfl_xor(p, 4);  // cross-quad (proven)
                if (wlane) *ops = p * 0.125f; // scale = D^-0.5
                ops += TS;
            }
        }
        __syncthreads();
    }

    if (MODE == 0) {
        float4* cw = (float4*)wsBase(c);
#pragma unroll
        for (int j = 0; j < 4; ++j) {
            float4 w;
            w.x = y[2 * j];     w.y = z[2 * j];
            w.z = y[2 * j + 1]; w.w = z[2 * j + 1];
            cw[j] = w;
        }
    }
}

extern "C" void kernel_launch(void* const* d_in, const int* in_sizes, int n_in,
                              void* d_out, int out_size, void* d_ws, size_t ws_size,
                              hipStream_t stream) {
    const float* q  = (const float*)d_in[0];
    const float* k  = (const float*)d_in[1];
    const float* v  = (const float*)d_in[2];
    const float* bt = (const float*)d_in[3];
    const float* ow = (const float*)d_in[4];
    const float* od = (const float*)d_in[5];
    float* out = (float*)d_out;
    float* ws = (float*)d_ws;

    const size_t chunkBytes = (size_t)128 * 2 * 4096 * sizeof(float); // 4 MiB

    if (ws_size >= 7 * chunkBytes) {
        // NC=8: L1 = chunks 0..6 (c0 full+ws, 1..6 state+ws); L2 = chunks 1..7.
        hipLaunchKernelGGL((linoss_k<8, 0>), dim3(1792), dim3(256), 0, stream,
                           q, k, v, bt, ow, od, out, ws, 0);
        hipLaunchKernelGGL((linoss_k<8, 1>), dim3(1792), dim3(256), 0, stream,
                           q, k, v, bt, ow, od, out, ws, 1);
    } else if (ws_size >= chunkBytes) {
        // NC=2: L1 = chunk 0 (full+ws); L2 = chunk 1.
        hipLaunchKernelGGL((linoss_k<2, 0>), dim3(256), dim3(256), 0, stream,
                           q, k, v, bt, ow, od, out, ws, 0);
        hipLaunchKernelGGL((linoss_k<2, 1>), dim3(256), dim3(256), 0, stream,
                           q, k, v, bt, ow, od, out, ws, 1);
    } else {
        // NC=1: single full sweep (c0=0 -> no prefix, q-dot, no ws).
        hipLaunchKernelGGL((linoss_k<1, 1>), dim3(256), dim3(256), 0, stream,
                           q, k, v, bt, ow, od, out, ws, 0);
    }
}